// Round 1
// baseline (25348.378 us; speedup 1.0000x reference)
//
#include <hip/hip_runtime.h>
#include <math.h>

#define GACC -9.80665f

__device__ __forceinline__ void mat3mul(const float* A, const float* B, float* C){
  #pragma unroll
  for (int r=0;r<3;r++)
    #pragma unroll
    for (int c=0;c<3;c++)
      C[r*3+c] = A[r*3]*B[c] + A[r*3+1]*B[3+c] + A[r*3+2]*B[6+c];
}

// skew(a)[r][c]
__device__ __forceinline__ float skew_el(const float* a, int r, int c){
  if (r==0) return (c==1)? -a[2] : ((c==2)? a[1] : 0.f);
  if (r==1) return (c==0)?  a[2] : ((c==2)? -a[0] : 0.f);
  return (c==0)? -a[1] : ((c==1)? a[0] : 0.f);
}

__device__ __forceinline__ void so3exp_f(const float* phi, float* R){
  float ang = sqrtf(phi[0]*phi[0]+phi[1]*phi[1]+phi[2]*phi[2]);
  float S[9] = {0.f,-phi[2],phi[1], phi[2],0.f,-phi[0], -phi[1],phi[0],0.f};
  if (ang < 1e-8f){
    #pragma unroll
    for (int k=0;k<9;k++) R[k] = ((k%4==0)?1.f:0.f) + S[k];
  } else {
    float SS[9]; mat3mul(S,S,SS);
    float c1 = sinf(ang)/ang;
    float c2 = (1.f-cosf(ang))/(ang*ang);
    #pragma unroll
    for (int k=0;k<9;k++) R[k] = ((k%4==0)?1.f:0.f) + c1*S[k] + c2*SS[k];
  }
}

__global__ __launch_bounds__(512)
void iekf_kernel(const float* __restrict__ t, const float* __restrict__ u,
                 const float* __restrict__ mcov, const float* __restrict__ vmes,
                 const float* __restrict__ ang0, const float* __restrict__ winit,
                 float* __restrict__ out, int N)
{
  const int tid = threadIdx.x;

  __shared__ float Ps[21][22];
  __shared__ float Fs[21][22];
  __shared__ float F2s[21][22];
  __shared__ float Phis[21][22];
  __shared__ float As[21][22];
  __shared__ float Bs[21][22];
  __shared__ float Gs[21][18];
  __shared__ float st[33];      // Rot 0-8, v 9-11, p 12-14, bo 15-17, ba 18-20, Rci 21-29, tci 30-32
  __shared__ float Hm[2][21];
  __shared__ float PHts[21][2];
  __shared__ float Km[21][2];
  __shared__ float dxs[21];
  __shared__ float Sv[3];
  __shared__ float rsh[2];

  const int i  = tid/21, j  = tid - i*21;     // valid for tid<441
  const int bi = i/3,  ri = i - bi*3;
  const int bj = j/3,  cj = j - bj*3;
  const int gi = tid/18, gk = tid - gi*18;    // valid for tid<378
  const int gbi = gi/3, gri = gi - gbi*3;
  const int gbk = gk/3, gck = gk - gbk*3;

  const float Qc[18] = {1e-3f,1e-3f,1e-3f, 1e-2f,1e-2f,1e-2f, 6e-9f,6e-9f,6e-9f,
                        2e-4f,2e-4f,2e-4f, 1e-9f,1e-9f,1e-9f, 1e-9f,1e-9f,1e-9f};

  // carry registers (meaningful only in thread 448)
  float Rr[9]={0}, vr[3]={0}, pr[3]={0}, bor[3]={0}, bar[3]={0}, Rcir[9]={0}, tcir[3]={0};

  // ---------------- init ----------------
  if (tid < 441) Ps[i][j] = 0.f;
  __syncthreads();
  if (tid == 448){
    float beta[6];
    #pragma unroll
    for (int k=0;k<6;k++) beta[k] = powf(10.f, tanhf(winit[k]));
    Ps[0][0]=0.001f*beta[0]; Ps[1][1]=0.001f*beta[0];
    Ps[3][3]=0.1f*beta[1];   Ps[4][4]=0.1f*beta[1];
    for (int c=9;c<12;c++)  Ps[c][c]=0.1f*beta[2];
    for (int c=12;c<15;c++) Ps[c][c]=0.1f*beta[3];
    for (int c=15;c<18;c++) Ps[c][c]=1e-6f*beta[4];
    for (int c=18;c<21;c++) Ps[c][c]=1e-5f*beta[5];
    // Rot0 = Rz(yaw)@Ry(pitch)@Rx(roll)
    float cr=cosf(ang0[0]), sr=sinf(ang0[0]);
    float cp=cosf(ang0[1]), sp=sinf(ang0[1]);
    float cy=cosf(ang0[2]), sy=sinf(ang0[2]);
    float Rz[9]={cy,-sy,0.f, sy,cy,0.f, 0.f,0.f,1.f};
    float Ry[9]={cp,0.f,sp, 0.f,1.f,0.f, -sp,0.f,cp};
    float Rx[9]={1.f,0.f,0.f, 0.f,cr,-sr, 0.f,sr,cr};
    float T1[9]; mat3mul(Rz,Ry,T1); mat3mul(T1,Rx,Rr);
    vr[0]=vmes[0]; vr[1]=vmes[1]; vr[2]=vmes[2];
    #pragma unroll
    for (int k=0;k<3;k++){ pr[k]=0.f; bor[k]=0.f; bar[k]=0.f; tcir[k]=0.f; }
    #pragma unroll
    for (int k=0;k<9;k++) Rcir[k] = (k%4==0)?1.f:0.f;
    #pragma unroll
    for (int k=0;k<9;k++) st[k]=Rr[k];
    #pragma unroll
    for (int k=0;k<3;k++){ st[9+k]=vr[k]; st[12+k]=0.f; st[15+k]=0.f; st[18+k]=0.f; st[30+k]=0.f; }
    #pragma unroll
    for (int k=0;k<9;k++) st[21+k]=Rcir[k];
  }
  __syncthreads();

  // prefetch for n=1
  float t_nm1 = t[0];
  float t_n   = (N>1)? t[1] : t[0];
  float mc0   = (N>1)? mcov[2] : 0.f;
  float mc1   = (N>1)? mcov[3] : 0.f;
  float u6[6] = {0,0,0,0,0,0};
  if (tid==448 && N>1){
    #pragma unroll
    for (int k=0;k<6;k++) u6[k]=u[6+k];
  }

  for (int n=1; n<N; n++){
    const float dtv = t_n - t_nm1;
    float Rnp[9], vnp[3], pnp[3];   // predicted state, thread 448 only
    #pragma unroll
    for (int k=0;k<9;k++) Rnp[k]=0.f;
    vnp[0]=vnp[1]=vnp[2]=0.f; pnp[0]=pnp[1]=pnp[2]=0.f;

    // ---------------- phase A: F, G build | scalar propagate + H,r | stream out row n-1
    if (tid < 441){
      float f = 0.f;
      if (bi==1 && bj==0){
        f = (ri==0 && cj==1)? -GACC : ((ri==1 && cj==0)? GACC : 0.f);
      } else if (bi==2 && bj==1){
        f = (ri==cj)? 1.f : 0.f;
      } else if (bi==0 && bj==3){
        f = -st[ri*3+cj];
      } else if (bi==1 && bj==4){
        f = -st[ri*3+cj];
      } else if (bi==1 && bj==3){
        float v0=st[9],v1=st[10],v2=st[11];
        float m;
        if (ri==0)      m = -v2*st[3+cj] + v1*st[6+cj];
        else if (ri==1) m =  v2*st[cj]   - v0*st[6+cj];
        else            m = -v1*st[cj]   + v0*st[3+cj];
        f = -m;
      } else if (bi==2 && bj==3){
        float p0=st[12],p1=st[13],p2=st[14];
        float m;
        if (ri==0)      m = -p2*st[3+cj] + p1*st[6+cj];
        else if (ri==1) m =  p2*st[cj]   - p0*st[6+cj];
        else            m = -p1*st[cj]   + p0*st[3+cj];
        f = -m;
      }
      Fs[i][j] = f*dtv;
    }
    if (tid < 378){
      float g = 0.f;
      if (gbi==0 && gbk==0)      g = st[gri*3+gck];
      else if (gbi==1 && gbk==1) g = st[gri*3+gck];
      else if (gbi==1 && gbk==0){
        float v0=st[9],v1=st[10],v2=st[11];
        if (gri==0)      g = -v2*st[3+gck] + v1*st[6+gck];
        else if (gri==1) g =  v2*st[gck]   - v0*st[6+gck];
        else             g = -v1*st[gck]   + v0*st[3+gck];
      } else if (gbi==2 && gbk==0){
        float p0=st[12],p1=st[13],p2=st[14];
        if (gri==0)      g = -p2*st[3+gck] + p1*st[6+gck];
        else if (gri==1) g =  p2*st[gck]   - p0*st[6+gck];
        else             g = -p1*st[gck]   + p0*st[3+gck];
      } else if (gbi==3 && gbk==2) g = (gri==gck)?1.f:0.f;
      else if (gbi==4 && gbk==3)   g = (gri==gck)?1.f:0.f;
      else if (gbi==5 && gbk==4)   g = (gri==gck)?1.f:0.f;
      else if (gbi==6 && gbk==5)   g = (gri==gck)?1.f:0.f;
      Gs[gi][gk] = g*dtv;
    }
    if (tid >= 449 && tid < 482){
      out[(size_t)(n-1)*33 + (tid-449)] = st[tid-449];
    }
    if (tid == 448){
      // propagate
      float ub[3] = {u6[3]-bar[0], u6[4]-bar[1], u6[5]-bar[2]};
      float acc[3];
      #pragma unroll
      for (int r=0;r<3;r++) acc[r] = Rr[r*3]*ub[0]+Rr[r*3+1]*ub[1]+Rr[r*3+2]*ub[2];
      acc[2] += GACC;
      #pragma unroll
      for (int r=0;r<3;r++){
        vnp[r] = vr[r] + acc[r]*dtv;
        pnp[r] = pr[r] + vr[r]*dtv + 0.5f*acc[r]*dtv*dtv;
      }
      float om[3] = {(u6[0]-bor[0])*dtv, (u6[1]-bor[1])*dtv, (u6[2]-bor[2])*dtv};
      float E[9]; so3exp_f(om, E);
      mat3mul(Rr, E, Rnp);
      // H and r (uses predicted Rot,v and previous Rci,tci,bo)
      float Rb[9]; mat3mul(Rnp, Rcir, Rb);           // Rot_body
      float vi[3];
      #pragma unroll
      for (int r=0;r<3;r++) vi[r] = Rnp[r]*vnp[0] + Rnp[3+r]*vnp[1] + Rnp[6+r]*vnp[2]; // Rot^T v
      float omm[3] = {u6[0]-bor[0], u6[1]-bor[1], u6[2]-bor[2]};
      float vb[3];
      #pragma unroll
      for (int r=0;r<3;r++){
        float sk = skew_el(tcir,r,0)*omm[0] + skew_el(tcir,r,1)*omm[1] + skew_el(tcir,r,2)*omm[2];
        vb[r] = Rcir[r]*vi[0] + Rcir[3+r]*vi[1] + Rcir[6+r]*vi[2] + sk;  // Rci^T v_imu + skew(tci) om
      }
      #pragma unroll
      for (int a=0;a<2;a++){
        int sr = 1+a;
        #pragma unroll
        for (int c=0;c<3;c++){
          Hm[a][c]    = 0.f;
          Hm[a][6+c]  = 0.f;
          Hm[a][12+c] = 0.f;
          Hm[a][3+c]  = Rb[c*3+sr];                   // Rot_body^T[sr][c]
          Hm[a][9+c]  = skew_el(tcir, sr, c);
          float hv = Rcir[sr]*skew_el(vi,0,c) + Rcir[3+sr]*skew_el(vi,1,c) + Rcir[6+sr]*skew_el(vi,2,c);
          Hm[a][15+c] = hv;                           // (Rci^T skew(v_imu))[sr][c]
          Hm[a][18+c] = -skew_el(omm, sr, c);
        }
        rsh[a] = -vb[sr];
      }
    }
    __syncthreads(); // 1

    // ---------------- phase B: F2 = F@F
    if (tid < 441){
      float a = 0.f;
      #pragma unroll
      for (int k=0;k<21;k++) a += Fs[i][k]*Fs[k][j];
      F2s[i][j] = a;
    }
    __syncthreads(); // 2

    // ---------------- phase C: Phi = I + F + F2/2 + (F2@F)/6 ; A = sym(P) + G Q G^T
    if (tid < 441){
      float a = 0.f;
      #pragma unroll
      for (int k=0;k<21;k++) a += F2s[i][k]*Fs[k][j];
      Phis[i][j] = ((i==j)?1.f:0.f) + Fs[i][j] + 0.5f*F2s[i][j] + a/6.0f;
      float s = 0.5f*(Ps[i][j]+Ps[j][i]);
      #pragma unroll
      for (int k=0;k<18;k++) s += Gs[i][k]*Qc[k]*Gs[j][k];
      As[i][j] = s;
    }
    __syncthreads(); // 3

    // ---------------- phase D: B = Phi @ A
    if (tid < 441){
      float a = 0.f;
      #pragma unroll
      for (int k=0;k<21;k++) a += Phis[i][k]*As[k][j];
      Bs[i][j] = a;
    }
    __syncthreads(); // 4

    // ---------------- phase E: P = B @ Phi^T
    if (tid < 441){
      float a = 0.f;
      #pragma unroll
      for (int k=0;k<21;k++) a += Bs[i][k]*Phis[j][k];
      Ps[i][j] = a;
    }
    __syncthreads(); // 5

    // ---------------- phase F: PHt = P @ H^T
    if (tid < 42){
      int ii = tid>>1, cc = tid&1;
      float a = 0.f;
      #pragma unroll
      for (int k=0;k<21;k++) a += Ps[ii][k]*Hm[cc][k];
      PHts[ii][cc] = a;
    }
    __syncthreads(); // 6

    // ---------------- phase G: S (redundant), K, dx
    if (tid < 21){
      float s00=mc0, s01=0.f, s10=0.f, s11=mc1;
      #pragma unroll
      for (int k=0;k<21;k++){
        s00 += Hm[0][k]*PHts[k][0];
        s01 += Hm[0][k]*PHts[k][1];
        s10 += Hm[1][k]*PHts[k][0];
        s11 += Hm[1][k]*PHts[k][1];
      }
      float det = s00*s11 - s01*s10;
      float id  = 1.f/det;
      float i00 =  s11*id, i01 = -s01*id, i10 = -s10*id, i11 = s00*id;
      float p0 = PHts[tid][0], p1 = PHts[tid][1];
      float k0 = p0*i00 + p1*i10;
      float k1 = p0*i01 + p1*i11;
      Km[tid][0]=k0; Km[tid][1]=k1;
      dxs[tid] = k0*rsh[0] + k1*rsh[1];
      if (tid==0){ Sv[0]=s00; Sv[1]=0.5f*(s01+s10); Sv[2]=s11; }
    }
    __syncthreads(); // 7

    // ---------------- phase H: rank-2 P update | scalar state retraction
    if (tid < 441){
      float ki0=Km[i][0], ki1=Km[i][1];
      float kj0=Km[j][0], kj1=Km[j][1];
      float pi0=PHts[i][0], pi1=PHts[i][1];
      float pj0=PHts[j][0], pj1=PHts[j][1];
      float tsum = (ki0*pj0 + ki1*pj1) + (pi0*kj0 + pi1*kj1);
      float quad = Sv[0]*(ki0*kj0) + Sv[1]*(ki0*kj1 + ki1*kj0) + Sv[2]*(ki1*kj1);
      Ps[i][j] = Ps[i][j] - tsum + quad;
    }
    if (tid == 448){
      float dxl[21];
      #pragma unroll
      for (int k=0;k<21;k++) dxl[k]=dxs[k];
      // sen3exp(dx[:9])
      float phi1[3]={dxl[0],dxl[1],dxl[2]};
      float ang = sqrtf(phi1[0]*phi1[0]+phi1[1]*phi1[1]+phi1[2]*phi1[2]);
      float S[9]={0.f,-phi1[2],phi1[1], phi1[2],0.f,-phi1[0], -phi1[1],phi1[0],0.f};
      float dR[9], Jm[9];
      if (ang < 1e-8f){
        #pragma unroll
        for (int k=0;k<9;k++){ float I=(k%4==0)?1.f:0.f; dR[k]=I+S[k]; Jm[k]=I+0.5f*S[k]; }
      } else {
        float SS[9]; mat3mul(S,S,SS);
        float sa=sinf(ang), ca=cosf(ang);
        float c1=sa/ang, c2=(1.f-ca)/(ang*ang), c3=(ang-sa)/(ang*ang*ang);
        #pragma unroll
        for (int k=0;k<9;k++){ float I=(k%4==0)?1.f:0.f; dR[k]=I+c1*S[k]+c2*SS[k]; Jm[k]=I+c2*S[k]+c3*SS[k]; }
      }
      float xv[3], xp[3];
      #pragma unroll
      for (int r=0;r<3;r++){
        xv[r]=Jm[r*3]*dxl[3]+Jm[r*3+1]*dxl[4]+Jm[r*3+2]*dxl[5];
        xp[r]=Jm[r*3]*dxl[6]+Jm[r*3+1]*dxl[7]+Jm[r*3+2]*dxl[8];
      }
      float Rn2[9]; mat3mul(dR, Rnp, Rn2);
      float vn2[3], pn2[3];
      #pragma unroll
      for (int r=0;r<3;r++){
        vn2[r]=dR[r*3]*vnp[0]+dR[r*3+1]*vnp[1]+dR[r*3+2]*vnp[2] + xv[r];
        pn2[r]=dR[r*3]*pnp[0]+dR[r*3+1]*pnp[1]+dR[r*3+2]*pnp[2] + xp[r];
      }
      #pragma unroll
      for (int r=0;r<3;r++){ bor[r]+=dxl[9+r]; bar[r]+=dxl[12+r]; }
      float E2[9]; so3exp_f(dxl+15, E2);
      float Rc2[9]; mat3mul(E2, Rcir, Rc2);
      #pragma unroll
      for (int k=0;k<9;k++) Rcir[k]=Rc2[k];
      #pragma unroll
      for (int r=0;r<3;r++) tcir[r]+=dxl[18+r];
      #pragma unroll
      for (int k=0;k<9;k++) Rr[k]=Rn2[k];
      #pragma unroll
      for (int r=0;r<3;r++){ vr[r]=vn2[r]; pr[r]=pn2[r]; }
      // commit state to LDS
      #pragma unroll
      for (int k=0;k<9;k++){ st[k]=Rr[k]; st[21+k]=Rcir[k]; }
      #pragma unroll
      for (int r=0;r<3;r++){ st[9+r]=vr[r]; st[12+r]=pr[r]; st[15+r]=bor[r]; st[18+r]=bar[r]; st[30+r]=tcir[r]; }
    }
    // prefetch next step's inputs
    {
      int np = n+1;
      t_nm1 = t_n;
      if (np < N){
        t_n = t[np];
        mc0 = mcov[np*2]; mc1 = mcov[np*2+1];
        if (tid==448){
          #pragma unroll
          for (int k=0;k<6;k++) u6[k]=u[np*6+k];
        }
      }
    }
    __syncthreads(); // 8
  }

  // final output row
  if (tid >= 449 && tid < 482){
    out[(size_t)(N-1)*33 + (tid-449)] = st[tid-449];
  }
}

extern "C" void kernel_launch(void* const* d_in, const int* in_sizes, int n_in,
                              void* d_out, int out_size, void* d_ws, size_t ws_size,
                              hipStream_t stream) {
  const float* t     = (const float*)d_in[0];
  const float* u     = (const float*)d_in[1];
  const float* mcov  = (const float*)d_in[2];
  const float* vmes  = (const float*)d_in[3];
  // d_in[4] = p_mes (unused by reference)
  const float* ang0  = (const float*)d_in[5];
  const float* winit = (const float*)d_in[6];
  float* out = (float*)d_out;
  int N = in_sizes[0];
  iekf_kernel<<<dim3(1), dim3(512), 0, stream>>>(t, u, mcov, vmes, ang0, winit, out, N);
}